// Round 4
// baseline (2666.845 us; speedup 1.0000x reference)
//
#include <hip/hip_runtime.h>
#include <hip/hip_bf16.h>
#include <math.h>

#define N1 50000
#define N2 50000
#define E1C 800000
#define E2C 800000
#define AC 10000
#define F 128
#define NSUP 25000
#define KHOPS 10
#define NEGINF -1e30f
#define NBINS 65536
#define NBINS22 (1 << 22)

static inline int cdiv(int a, int b) { return (a + b - 1) / b; }

// ---------------- bf16 helpers ----------------
__device__ __forceinline__ float bf2f(unsigned short u) {
  return __uint_as_float(((unsigned)u) << 16);
}
__device__ __forceinline__ unsigned short f2bf(float f) {
  unsigned x = __float_as_uint(f);
  return (unsigned short)((x + 0x7FFFu + ((x >> 16) & 1u)) >> 16);
}

// ---------------- CSR build ----------------
__global__ void k_count(const int* __restrict__ key, int* __restrict__ cnt, int n) {
  int e = blockIdx.x * blockDim.x + threadIdx.x;
  if (e < n) atomicAdd(&cnt[key[e]], 1);
}

// single-block scan: thread-sequential partials + shuffle scan
__global__ void k_scan(const int* __restrict__ cnt, int* __restrict__ rowptr, int n) {
  const int T = 1024;
  int t = threadIdx.x;
  int vpt = (n + T - 1) / T;
  int lo = t * vpt, hi = lo + vpt;
  if (hi > n) hi = n;
  int sum = 0;
  for (int i = lo; i < hi; ++i) sum += cnt[i];
  int lane = t & 63, wid = t >> 6;
  int v = sum;
#pragma unroll
  for (int o = 1; o < 64; o <<= 1) {
    int u = __shfl_up(v, o, 64);
    if (lane >= o) v += u;
  }
  __shared__ int wsum[16];
  if (lane == 63) wsum[wid] = v;
  __syncthreads();
  if (t < 16) {
    int w = wsum[t];
#pragma unroll
    for (int o = 1; o < 16; o <<= 1) {
      int u = __shfl_up(w, o, 64);
      if (t >= o) w += u;
    }
    wsum[t] = w;
  }
  __syncthreads();
  int base = (wid ? wsum[wid - 1] : 0) + (v - sum);
  if (t == 0) rowptr[0] = 0;
  int run = base;
  for (int i = lo; i < hi; ++i) { run += cnt[i]; rowptr[i + 1] = run; }
}

__global__ void k_fill(const int* __restrict__ key, const int* __restrict__ payload,
                       const float* __restrict__ val, const int* __restrict__ rowptr,
                       int* __restrict__ cnt, int* __restrict__ col, float* __restrict__ v,
                       int n) {
  int e = blockIdx.x * blockDim.x + threadIdx.x;
  if (e < n) {
    int k = key[e];
    int p = atomicAdd(&cnt[k], 1);
    int s = rowptr[k] + p;
    col[s] = payload[e];
    if (val) v[s] = val[e];
  }
}

// fill storing the element index itself (for cluster->member lists)
__global__ void k_fill_iota(const int* __restrict__ key, const int* __restrict__ rowptr,
                            int* __restrict__ cnt, int* __restrict__ col, int n) {
  int e = blockIdx.x * blockDim.x + threadIdx.x;
  if (e < n) {
    int k = key[e];
    int p = atomicAdd(&cnt[k], 1);
    col[rowptr[k] + p] = e;
  }
}

__global__ void k_count_coarse(const int* __restrict__ dst, const int* __restrict__ cluster,
                               int* __restrict__ cnt, int n) {
  int e = blockIdx.x * blockDim.x + threadIdx.x;
  if (e < n) atomicAdd(&cnt[cluster[dst[e]]], 1);
}

// coarse fill computing cw = w * a[src] * a[dst] inline
__global__ void k_fill_coarse(const int* __restrict__ src, const int* __restrict__ dst,
                              const int* __restrict__ cluster, const float* __restrict__ w,
                              const float* __restrict__ a, const int* __restrict__ rowptr,
                              int* __restrict__ cnt, int* __restrict__ col,
                              float* __restrict__ v, int n) {
  int e = blockIdx.x * blockDim.x + threadIdx.x;
  if (e < n) {
    int sd = dst[e];
    int k = cluster[sd];
    int p = atomicAdd(&cnt[k], 1);
    int s = rowptr[k] + p;
    int ss = src[e];
    col[s] = cluster[ss];
    v[s] = w[e] * a[ss] * a[sd];
  }
}

// ---------------- degree via CSR rowsum (no atomics) ----------------
__global__ void k_rowsum(const int* __restrict__ rowptr, const float* __restrict__ v,
                         float* __restrict__ deg, int n) {
  int i = blockIdx.x * blockDim.x + threadIdx.x;
  if (i >= n) return;
  int s0 = rowptr[i], s1 = rowptr[i + 1];
  float s = 0.f;
  for (int k = s0; k < s1; ++k) s += v[k];
  deg[i] = s;
}

// in-place symmetric normalization of CSR values
__global__ void k_csrnorm(const int* __restrict__ rowptr, const int* __restrict__ col,
                          float* __restrict__ v, const float* __restrict__ deg, int n) {
  int i = blockIdx.x * blockDim.x + threadIdx.x;
  if (i >= n) return;
  int s0 = rowptr[i], s1 = rowptr[i + 1];
  float di = deg[i] + 1.f;
  for (int s = s0; s < s1; s += 4) {
    int c[4]; bool ok[4];
#pragma unroll
    for (int j = 0; j < 4; ++j) {
      int ss = s + j;
      ok[j] = ss < s1;
      c[j] = col[ok[j] ? ss : (s1 - 1)];
    }
    float dc[4];
#pragma unroll
    for (int j = 0; j < 4; ++j) dc[j] = deg[c[j]];
#pragma unroll
    for (int j = 0; j < 4; ++j)
      if (ok[j]) v[s + j] = v[s + j] / sqrtf((dc[j] + 1.f) * di);
  }
}

// ---------------- propagation fp32 (pull, 32 threads/node, 8-edge groups) -------------
__global__ void k_prop(const float4* __restrict__ hin, float4* __restrict__ hout,
                       float4* __restrict__ relu_out, const int* __restrict__ rowptr,
                       const int* __restrict__ col, const float* __restrict__ val, int n) {
  int node = blockIdx.x * 8 + (threadIdx.x >> 5);
  if (node >= n) return;
  int q = threadIdx.x & 31;
  int s0 = rowptr[node], s1 = rowptr[node + 1];
  float4 acc = make_float4(0.f, 0.f, 0.f, 0.f);
  for (int s = s0; s < s1; s += 8) {
    int c[8]; float v[8];
#pragma unroll
    for (int j = 0; j < 8; ++j) {
      int ss = s + j;
      int sc = (ss < s1) ? ss : (s1 - 1);
      c[j] = col[sc];
      v[j] = (ss < s1) ? val[sc] : 0.f;
    }
    float4 h[8];
#pragma unroll
    for (int j = 0; j < 8; ++j) h[j] = hin[(size_t)c[j] * 32 + q];
#pragma unroll
    for (int j = 0; j < 8; ++j) {
      acc.x = fmaf(v[j], h[j].x, acc.x);
      acc.y = fmaf(v[j], h[j].y, acc.y);
      acc.z = fmaf(v[j], h[j].z, acc.z);
      acc.w = fmaf(v[j], h[j].w, acc.w);
    }
  }
  hout[(size_t)node * 32 + q] = acc;
  if (relu_out) {
    float4 r;
    r.x = fmaxf(acc.x, 0.f); r.y = fmaxf(acc.y, 0.f);
    r.z = fmaxf(acc.z, 0.f); r.w = fmaxf(acc.w, 0.f);
    relu_out[(size_t)node * 32 + q] = r;
  }
}

// ---------------- propagation bf16 (graph-2, decision-free path) ----------------
__global__ void k_prop_bf16(const ushort4* __restrict__ hin, ushort4* __restrict__ hout,
                            float4* __restrict__ fout, const int* __restrict__ rowptr,
                            const int* __restrict__ col, const float* __restrict__ val, int n) {
  int node = blockIdx.x * 8 + (threadIdx.x >> 5);
  if (node >= n) return;
  int q = threadIdx.x & 31;
  int s0 = rowptr[node], s1 = rowptr[node + 1];
  float4 acc = make_float4(0.f, 0.f, 0.f, 0.f);
  for (int s = s0; s < s1; s += 8) {
    int c[8]; float v[8];
#pragma unroll
    for (int j = 0; j < 8; ++j) {
      int ss = s + j;
      int sc = (ss < s1) ? ss : (s1 - 1);
      c[j] = col[sc];
      v[j] = (ss < s1) ? val[sc] : 0.f;
    }
    ushort4 h[8];
#pragma unroll
    for (int j = 0; j < 8; ++j) h[j] = hin[(size_t)c[j] * 32 + q];
#pragma unroll
    for (int j = 0; j < 8; ++j) {
      acc.x = fmaf(v[j], bf2f(h[j].x), acc.x);
      acc.y = fmaf(v[j], bf2f(h[j].y), acc.y);
      acc.z = fmaf(v[j], bf2f(h[j].z), acc.z);
      acc.w = fmaf(v[j], bf2f(h[j].w), acc.w);
    }
  }
  if (fout) {
    fout[(size_t)node * 32 + q] = acc;
  } else {
    ushort4 o;
    o.x = f2bf(acc.x); o.y = f2bf(acc.y); o.z = f2bf(acc.z); o.w = f2bf(acc.w);
    hout[(size_t)node * 32 + q] = o;
  }
}

// ---------------- dense matmul out = relu?(X @ W + b), W given transposed ----------------
__global__ void k_transpose(const float* __restrict__ W, float* __restrict__ WT) {
  int i = blockIdx.x * blockDim.x + threadIdx.x;
  if (i < F * F) { int k = i >> 7, c = i & 127; WT[c * F + k] = W[i]; }
}

__global__ void k_mm128(const float* __restrict__ X, const float* __restrict__ WT,
                        const float* __restrict__ bias, float* __restrict__ out,
                        int M, int relu) {
  __shared__ float4 xs[16][32];
  int tid = threadIdx.x;
  int c = tid & 127;
  int half = tid >> 7;
  int row0 = blockIdx.x * 16;
  for (int t = tid; t < 512; t += 256) {
    int r = t >> 5, k4 = t & 31;
    int gr = row0 + r;
    float4 v = make_float4(0.f, 0.f, 0.f, 0.f);
    if (gr < M) v = ((const float4*)X)[(size_t)gr * 32 + k4];
    xs[r][k4] = v;
  }
  __syncthreads();
  float acc[8];
#pragma unroll
  for (int r = 0; r < 8; ++r) acc[r] = 0.f;
  const float4* wrow = (const float4*)WT + (size_t)c * 32;
  for (int k4 = 0; k4 < 32; ++k4) {
    float4 w = wrow[k4];
#pragma unroll
    for (int r = 0; r < 8; ++r) {
      float4 xv = xs[half * 8 + r][k4];
      acc[r] = fmaf(xv.x, w.x, acc[r]);
      acc[r] = fmaf(xv.y, w.y, acc[r]);
      acc[r] = fmaf(xv.z, w.z, acc[r]);
      acc[r] = fmaf(xv.w, w.w, acc[r]);
    }
  }
  float bb = bias ? bias[c] : 0.f;
#pragma unroll
  for (int r = 0; r < 8; ++r) {
    int gr = row0 + half * 8 + r;
    if (gr < M) {
      float v = acc[r] + bb;
      if (relu) v = fmaxf(v, 0.f);
      out[(size_t)gr * F + c] = v;
    }
  }
}

// same as k_mm128 but bf16 output
__global__ void k_mm128_bf16(const float* __restrict__ X, const float* __restrict__ WT,
                             const float* __restrict__ bias, unsigned short* __restrict__ out,
                             int M) {
  __shared__ float4 xs[16][32];
  int tid = threadIdx.x;
  int c = tid & 127;
  int half = tid >> 7;
  int row0 = blockIdx.x * 16;
  for (int t = tid; t < 512; t += 256) {
    int r = t >> 5, k4 = t & 31;
    int gr = row0 + r;
    float4 v = make_float4(0.f, 0.f, 0.f, 0.f);
    if (gr < M) v = ((const float4*)X)[(size_t)gr * 32 + k4];
    xs[r][k4] = v;
  }
  __syncthreads();
  float acc[8];
#pragma unroll
  for (int r = 0; r < 8; ++r) acc[r] = 0.f;
  const float4* wrow = (const float4*)WT + (size_t)c * 32;
  for (int k4 = 0; k4 < 32; ++k4) {
    float4 w = wrow[k4];
#pragma unroll
    for (int r = 0; r < 8; ++r) {
      float4 xv = xs[half * 8 + r][k4];
      acc[r] = fmaf(xv.x, w.x, acc[r]);
      acc[r] = fmaf(xv.y, w.y, acc[r]);
      acc[r] = fmaf(xv.z, w.z, acc[r]);
      acc[r] = fmaf(xv.w, w.w, acc[r]);
    }
  }
  float bb = bias ? bias[c] : 0.f;
#pragma unroll
  for (int r = 0; r < 8; ++r) {
    int gr = row0 + half * 8 + r;
    if (gr < M) out[(size_t)gr * F + c] = f2bf(acc[r] + bb);
  }
}

// ---------------- elementwise ----------------
__global__ void k_addrelu(const float* __restrict__ a, const float* __restrict__ b,
                          float* __restrict__ out, int n) {
  int i = blockIdx.x * blockDim.x + threadIdx.x;
  if (i < n) out[i] = fmaxf(a[i] + b[i], 0.f);
}

// ---------------- scores + ranking (top-k via 22-bit bin bucketing) ----------------
__global__ void k_score(const float* __restrict__ xr, const float* __restrict__ p,
                        float* __restrict__ s, int n) {
  int wid = (blockIdx.x * blockDim.x + threadIdx.x) >> 6;
  int lane = threadIdx.x & 63;
  if (wid >= n) return;
  const float* row = xr + (size_t)wid * F;
  float d = row[lane] * p[lane] + row[lane + 64] * p[lane + 64];
#pragma unroll
  for (int o = 32; o; o >>= 1) d += __shfl_xor(d, o, 64);
  if (lane == 0) s[wid] = d;
}

__device__ __forceinline__ unsigned sortkey(float f) {
  if (f == 0.f) f = 0.f;  // canonicalize -0 -> +0
  unsigned u = __float_as_uint(f);
  return (u & 0x80000000u) ? ~u : (u | 0x80000000u);
}

__global__ void k_key(const float* __restrict__ s, unsigned* __restrict__ key, int n) {
  int i = blockIdx.x * blockDim.x + threadIdx.x;
  if (i < n) key[i] = sortkey(s[i]);
}

__global__ void k_count_bins22(const unsigned* __restrict__ key, int* __restrict__ cnt, int n) {
  int i = blockIdx.x * blockDim.x + threadIdx.x;
  if (i < n) atomicAdd(&cnt[key[i] >> 10], 1);
}

// block sums over 1024-bin chunks (grid = NBINS22/1024 = 4096 blocks, 256 thr)
__global__ void k_hist_blocksum(const int* __restrict__ cnt, int* __restrict__ partial) {
  int t = threadIdx.x;
  int base = blockIdx.x * 1024 + t * 4;
  int s = cnt[base] + cnt[base + 1] + cnt[base + 2] + cnt[base + 3];
#pragma unroll
  for (int o = 32; o; o >>= 1) s += __shfl_down(s, o, 64);
  __shared__ int ws[4];
  int lane = t & 63, w = t >> 6;
  if (lane == 0) ws[w] = s;
  __syncthreads();
  if (t == 0) partial[blockIdx.x] = ws[0] + ws[1] + ws[2] + ws[3];
}

// apply scanned partials: binptr[b+1] = global inclusive prefix
__global__ void k_hist_apply(const int* __restrict__ cnt, const int* __restrict__ partialptr,
                             int* __restrict__ binptr) {
  int t = threadIdx.x;
  int base = blockIdx.x * 1024 + t * 4;
  int c0 = cnt[base], c1 = cnt[base + 1], c2 = cnt[base + 2], c3 = cnt[base + 3];
  int s = c0 + c1 + c2 + c3;
  int lane = t & 63, w = t >> 6;
  int v = s;
#pragma unroll
  for (int o = 1; o < 64; o <<= 1) {
    int u = __shfl_up(v, o, 64);
    if (lane >= o) v += u;
  }
  __shared__ int ws[4];
  if (lane == 63) ws[w] = v;
  __syncthreads();
  int wb = 0;
  for (int i = 0; i < w; ++i) wb += ws[i];
  int run = partialptr[blockIdx.x] + wb + (v - s);
  binptr[base + 1] = run + c0;
  binptr[base + 2] = run + c0 + c1;
  binptr[base + 3] = run + c0 + c1 + c2;
  binptr[base + 4] = run + s;
  if (blockIdx.x == 0 && t == 0) binptr[0] = 0;
}

__global__ void k_fill_bins22(const unsigned* __restrict__ key, const int* __restrict__ binptr,
                              int* __restrict__ cnt, int* __restrict__ bidx,
                              unsigned* __restrict__ bkey, int n) {
  int i = blockIdx.x * blockDim.x + threadIdx.x;
  if (i < n) {
    unsigned k = key[i];
    int b = k >> 10;
    int p = atomicAdd(&cnt[b], 1);
    int s = binptr[b] + p;
    bidx[s] = i;
    bkey[s] = k;
  }
}

// rank_i = #{j: s_j > s_i} + #{j: s_j == s_i && j < i}; supid = rank < NSUP ? rank : -1
__global__ void k_rank22(const unsigned* __restrict__ key, const int* __restrict__ binptr,
                         const int* __restrict__ bidx, const unsigned* __restrict__ bkey,
                         int* __restrict__ supid, int n) {
  int i = blockIdx.x * blockDim.x + threadIdx.x;
  if (i >= n) return;
  unsigned ki = key[i];
  int b = ki >> 10;
  int cnt = n - binptr[b + 1];  // all keys in strictly-higher bins
  int s1 = binptr[b + 1];
  for (int s = binptr[b]; s < s1; ++s) {
    unsigned kj = bkey[s];
    cnt += (kj > ki) || (kj == ki && bidx[s] < i);
  }
  supid[i] = (cnt < NSUP) ? cnt : -1;
}

// ---------------- attention / assignment ----------------
__device__ __forceinline__ float read_T(const void* p) {
  int ib = *(const int*)p;
  float fb = __int_as_float(ib);
  if (ib >= 1 && ib < (1 << 20)) return (float)ib;   // int-encoded scalar
  if (fb > 1e-6f && fb < 1e6f) return fb;            // float-encoded scalar
  return 1.0f;
}

// wave per node; 4-edge groups for gather MLP
__global__ void k_att_a(const float* __restrict__ xr, const int* __restrict__ rowptr,
                        const int* __restrict__ col, const int* __restrict__ supid,
                        const void* __restrict__ tptr, float* __restrict__ att,
                        float* __restrict__ attself, float* __restrict__ mout, int n) {
  int wid = (blockIdx.x * blockDim.x + threadIdx.x) >> 6;
  int lane = threadIdx.x & 63;
  if (wid >= n) return;
  float inv = 1.0f / (sqrtf(128.0f) * read_T(tptr));
  const float* xn = xr + (size_t)wid * F;
  float x0 = xn[lane], x1 = xn[lane + 64];
  // self candidate
  float d = x0 * x0 + x1 * x1;
#pragma unroll
  for (int o = 32; o; o >>= 1) d += __shfl_xor(d, o, 64);
  float av = (supid[wid] >= 0) ? d * inv : NEGINF;
  float m = av;
  if (lane == 0) attself[wid] = av;
  int s0 = rowptr[wid], s1 = rowptr[wid + 1];
  for (int s = s0; s < s1; s += 4) {
    int c[4]; bool ok[4];
#pragma unroll
    for (int j = 0; j < 4; ++j) {
      int ss = s + j;
      ok[j] = ss < s1;
      c[j] = col[ok[j] ? ss : (s1 - 1)];
    }
    float dd[4];
#pragma unroll
    for (int j = 0; j < 4; ++j) {
      const float* xc = xr + (size_t)c[j] * F;
      dd[j] = x0 * xc[lane] + x1 * xc[lane + 64];
    }
#pragma unroll
    for (int j = 0; j < 4; ++j) {
#pragma unroll
      for (int o = 32; o; o >>= 1) dd[j] += __shfl_xor(dd[j], o, 64);
    }
#pragma unroll
    for (int j = 0; j < 4; ++j) {
      if (ok[j]) {
        float a2 = (supid[c[j]] >= 0) ? dd[j] * inv : NEGINF;
        if (lane == 0) att[s + j] = a2;
        m = fmaxf(m, a2);
      }
    }
  }
  if (lane == 0) mout[wid] = m;
}

// a[n] = has ? 1/esum : 0  (argmax candidates have exp(att-m)=exp(0)=1 exactly)
__global__ void k_att_b(const int* __restrict__ rowptr, const int* __restrict__ col,
                        const int* __restrict__ supid, const float* __restrict__ att,
                        const float* __restrict__ attself, const float* __restrict__ mv,
                        int* __restrict__ cluster, float* __restrict__ aout, int n) {
  int i = blockIdx.x * blockDim.x + threadIdx.x;
  if (i >= n) return;
  float m = mv[i];
  float as = attself[i];
  float esum = expf(as - m);
  int best = -1;
  if (as >= m) {
    int sid = supid[i];
    if (sid > best) best = sid;
  }
  int s0 = rowptr[i], s1 = rowptr[i + 1];
  for (int s = s0; s < s1; ++s) {
    float av = att[s];
    esum += expf(av - m);
    if (av >= m) {
      int sid = supid[col[s]];
      if (sid > best) best = sid;
    }
  }
  int has = best >= 0;
  cluster[i] = has ? best : 0;
  aout[i] = has ? 1.0f / esum : 0.0f;
}

// ---------------- pooling (pull over cluster->member CSR) ----------------
__global__ void k_xpool_pull(const float4* __restrict__ xr, const float* __restrict__ a,
                             const int* __restrict__ rowptrM, const int* __restrict__ memb,
                             float4* __restrict__ xpool, int n) {
  int c = blockIdx.x * 8 + (threadIdx.x >> 5);
  if (c >= n) return;
  int q = threadIdx.x & 31;
  int s0 = rowptrM[c], s1 = rowptrM[c + 1];
  float4 acc = make_float4(0.f, 0.f, 0.f, 0.f);
  for (int s = s0; s < s1; ++s) {
    int m = memb[s];
    float av = a[m];
    float4 h = xr[(size_t)m * 32 + q];
    acc.x = fmaf(av, h.x, acc.x);
    acc.y = fmaf(av, h.y, acc.y);
    acc.z = fmaf(av, h.z, acc.z);
    acc.w = fmaf(av, h.w, acc.w);
  }
  xpool[(size_t)c * 32 + q] = acc;
}

// ---------------- anchor scatters ----------------
__global__ void k_scatter_q(const int* __restrict__ a1, const int* __restrict__ a2,
                            const int* __restrict__ cluster, const float* __restrict__ aarr,
                            const float* __restrict__ t1, float* __restrict__ outy, int nA) {
  int idx = blockIdx.x * blockDim.x + threadIdx.x;
  if (idx >= nA * F) return;
  int k = idx >> 7, f = idx & 127;
  int n1 = a1[k];
  float qw = aarr[n1];
  if (qw != 0.f)
    atomicAdd(&outy[(size_t)a2[k] * F + f], qw * t1[(size_t)cluster[n1] * F + f]);
}

__global__ void k_scatter_t2(const int* __restrict__ a1, const int* __restrict__ a2,
                             const float* __restrict__ t2, float* __restrict__ outy, int nA) {
  int idx = blockIdx.x * blockDim.x + threadIdx.x;
  if (idx >= nA * F) return;
  int k = idx >> 7, f = idx & 127;
  atomicAdd(&outy[(size_t)a2[k] * F + f], t2[(size_t)a1[k] * F + f]);
}

// ================= host =================
extern "C" void kernel_launch(void* const* d_in, const int* in_sizes, int n_in,
                              void* d_out, int out_size, void* d_ws, size_t ws_size,
                              hipStream_t stream) {
  (void)in_sizes; (void)n_in; (void)out_size; (void)ws_size;
  const float* x   = (const float*)d_in[0];
  const int*   ei  = (const int*)d_in[1];     // src = ei, dst = ei+E1C
  const float* w1  = (const float*)d_in[2];
  const float* y   = (const float*)d_in[3];
  const int*   eiy = (const int*)d_in[4];
  const float* wy  = (const float*)d_in[5];
  const int*   anc = (const int*)d_in[6];     // a1 = anc, a2 = anc+AC
  const void*  tmp = d_in[7];
  const float* W_gcn = (const float*)d_in[8];
  const float* b_gcn = (const float*)d_in[9];
  const float* p_sc  = (const float*)d_in[10];
  const float* W_c1  = (const float*)d_in[11];
  const float* b_c1  = (const float*)d_in[12];
  const float* W_m1  = (const float*)d_in[13];
  const float* b_m1  = (const float*)d_in[14];
  const float* W_l1  = (const float*)d_in[15];
  const float* W_l2  = (const float*)d_in[16];
  const float* W_m2  = (const float*)d_in[17];
  const float* b_m2  = (const float*)d_in[18];

  float* out   = (float*)d_out;
  float* out_x = out;
  float* sup1  = out_x + (size_t)N1 * F;
  float* out_y = sup1 + (size_t)NSUP * F;
  float* sup2  = out_y + (size_t)N2 * F;
  float* a_out = sup2 + (size_t)NSUP * F;
  float* recon = a_out + N1;

  char* wsb = (char*)d_ws;
  size_t off = 0;
  auto alloc = [&](size_t bytes) -> void* {
    void* p = wsb + off;
    off = (off + bytes + 255) & ~(size_t)255;
    return p;
  };
  float*    f_csr1v   = (float*)alloc((size_t)E1C * 4);          // reused for graph2 CSR val
  int*      i_csr1c   = (int*)alloc((size_t)E1C * 4);            // reused for graph2 CSR col
  int*      i_rowptr1 = (int*)alloc((size_t)(N1 + 1) * 4);       // reused for graph2
  float*    f_deg     = (float*)alloc((size_t)N1 * 4);           // reused for graph2
  int*      i_cnt     = (int*)alloc((size_t)(NBINS + 1) * 4);
  float*    f_ha      = (float*)alloc((size_t)N1 * F * 4);       // g1 h / cnt22 / g2 bf16 h_a
  float*    f_hb      = (float*)alloc((size_t)N1 * F * 4);       // g1 h / binptr22 / g2 bf16 h_b
  float*    f_xr      = (float*)alloc((size_t)N1 * F * 4);       // reused for t2
  float*    f_s       = (float*)alloc((size_t)N1 * 4);
  unsigned* u_key     = (unsigned*)alloc((size_t)N1 * 4);
  int*      i_partial = (int*)alloc((size_t)4096 * 4);
  int*      i_partptr = (int*)alloc((size_t)4097 * 4);
  int*      i_bidx    = (int*)alloc((size_t)N1 * 4);
  unsigned* u_bkey    = (unsigned*)alloc((size_t)N1 * 4);
  int*      i_supid   = (int*)alloc((size_t)N1 * 4);
  int*      i_rowptrS = (int*)alloc((size_t)(N1 + 1) * 4);
  int*      i_csrSc   = (int*)alloc((size_t)E1C * 4);
  float*    f_att     = (float*)alloc((size_t)E1C * 4);
  float*    f_attself = (float*)alloc((size_t)N1 * 4);
  float*    f_m       = (float*)alloc((size_t)N1 * 4);
  int*      i_cluster = (int*)alloc((size_t)N1 * 4);
  float*    f_xpool   = (float*)alloc((size_t)NSUP * F * 4);
  float*    f_degc    = (float*)alloc((size_t)NSUP * 4);
  int*      i_rowptrC = (int*)alloc((size_t)(NSUP + 1) * 4);
  int*      i_csrCc   = (int*)alloc((size_t)E1C * 4);
  float*    f_csrCv   = (float*)alloc((size_t)E1C * 4);
  int*      i_rowptrM = (int*)alloc((size_t)(NSUP + 1) * 4);
  int*      i_memb    = (int*)alloc((size_t)N1 * 4);
  float*    f_h2      = (float*)alloc((size_t)NSUP * F * 4);
  float*    f_h2p     = (float*)alloc((size_t)NSUP * F * 4);     // reused for t1
  float*    f_wt      = (float*)alloc((size_t)6 * F * F * 4);

  // overlays: rank bins live between graph-1 and graph-2; bf16 h lives in graph-2 only
  int* i_cnt22    = (int*)f_ha;       // 16 MB <= 25.6 MB
  int* i_binptr22 = (int*)f_hb;       // 16 MB + 4 <= 25.6 MB
  unsigned short* h16a = (unsigned short*)f_ha;   // 12.8 MB
  unsigned short* h16b = (unsigned short*)f_hb;   // 12.8 MB

  const int* src1 = ei,  * dst1 = ei + E1C;
  const int* srcy = eiy, * dsty = eiy + E2C;
  const int* a1 = anc, * a2 = anc + AC;

  // --- transpose all weights ---
  const float* Ws[6] = { W_gcn, W_c1, W_m1, W_l1, W_l2, W_m2 };
  for (int i = 0; i < 6; ++i)
    k_transpose<<<cdiv(F * F, 256), 256, 0, stream>>>(Ws[i], f_wt + (size_t)i * F * F);
  float* wt_gcn = f_wt, *wt_c1 = f_wt + 16384, *wt_m1 = f_wt + 2 * 16384,
       * wt_l1 = f_wt + 3 * 16384, *wt_l2 = f_wt + 4 * 16384, *wt_m2 = f_wt + 5 * 16384;

  int gE = cdiv(E1C, 256);
  int gN = cdiv(N1, 256);

  // --- CSR graph1 by dst, with raw w; then deg=rowsum, normalize in place ---
  hipMemsetAsync(i_cnt, 0, (size_t)(NBINS + 1) * 4, stream);
  k_count<<<gE, 256, 0, stream>>>(dst1, i_cnt, E1C);
  k_scan<<<1, 1024, 0, stream>>>(i_cnt, i_rowptr1, N1);
  hipMemsetAsync(i_cnt, 0, (size_t)(NBINS + 1) * 4, stream);
  k_fill<<<gE, 256, 0, stream>>>(dst1, src1, w1, i_rowptr1, i_cnt, i_csr1c, f_csr1v, E1C);
  k_rowsum<<<gN, 256, 0, stream>>>(i_rowptr1, f_csr1v, f_deg, N1);
  k_csrnorm<<<gN, 256, 0, stream>>>(i_rowptr1, i_csr1c, f_csr1v, f_deg, N1);

  // --- GCN graph1: h0 = x@W + b; 10 hops (fp32 — feeds top-k/argmax decisions) ---
  k_mm128<<<cdiv(N1, 16), 256, 0, stream>>>(x, wt_gcn, b_gcn, f_ha, N1, 0);
  {
    const float* cur = f_ha;
    for (int i = 0; i < KHOPS; ++i) {
      int last = (i == KHOPS - 1);
      float* dst = last ? out_x : ((i & 1) ? f_ha : f_hb);
      k_prop<<<cdiv(N1, 8), 256, 0, stream>>>((const float4*)cur, (float4*)dst,
                                              last ? (float4*)f_xr : nullptr,
                                              i_rowptr1, i_csr1c, f_csr1v, N1);
      cur = dst;
    }
  }

  // --- scores + top-k ranks (22-bit bins) ---
  k_score<<<cdiv(N1, 4), 256, 0, stream>>>(f_xr, p_sc, f_s, N1);
  k_key<<<gN, 256, 0, stream>>>(f_s, u_key, N1);
  hipMemsetAsync(i_cnt22, 0, (size_t)NBINS22 * 4, stream);
  k_count_bins22<<<gN, 256, 0, stream>>>(u_key, i_cnt22, N1);
  k_hist_blocksum<<<NBINS22 / 1024, 256, 0, stream>>>(i_cnt22, i_partial);
  k_scan<<<1, 1024, 0, stream>>>(i_partial, i_partptr, 4096);
  k_hist_apply<<<NBINS22 / 1024, 256, 0, stream>>>(i_cnt22, i_partptr, i_binptr22);
  hipMemsetAsync(i_cnt22, 0, (size_t)NBINS22 * 4, stream);
  k_fill_bins22<<<gN, 256, 0, stream>>>(u_key, i_binptr22, i_cnt22, i_bidx, u_bkey, N1);
  k_rank22<<<gN, 256, 0, stream>>>(u_key, i_binptr22, i_bidx, u_bkey, i_supid, N1);

  // --- CSR graph1 by src (attention candidates) ---
  hipMemsetAsync(i_cnt, 0, (size_t)(NBINS + 1) * 4, stream);
  k_count<<<gE, 256, 0, stream>>>(src1, i_cnt, E1C);
  k_scan<<<1, 1024, 0, stream>>>(i_cnt, i_rowptrS, N1);
  hipMemsetAsync(i_cnt, 0, (size_t)(NBINS + 1) * 4, stream);
  k_fill<<<gE, 256, 0, stream>>>(src1, dst1, (const float*)nullptr, i_rowptrS, i_cnt, i_csrSc,
                                 (float*)nullptr, E1C);

  // --- attention passes ---
  k_att_a<<<cdiv(N1, 4), 256, 0, stream>>>(f_xr, i_rowptrS, i_csrSc, i_supid, tmp,
                                           f_att, f_attself, f_m, N1);
  k_att_b<<<gN, 256, 0, stream>>>(i_rowptrS, i_csrSc, i_supid, f_att, f_attself,
                                  f_m, i_cluster, a_out, N1);

  // --- coarsen: cluster->member CSR + pull pooling (no fp32 atomics) ---
  hipMemsetAsync(i_cnt, 0, (size_t)(NBINS + 1) * 4, stream);
  k_count<<<gN, 256, 0, stream>>>(i_cluster, i_cnt, N1);
  k_scan<<<1, 1024, 0, stream>>>(i_cnt, i_rowptrM, NSUP);
  hipMemsetAsync(i_cnt, 0, (size_t)(NBINS + 1) * 4, stream);
  k_fill_iota<<<gN, 256, 0, stream>>>(i_cluster, i_rowptrM, i_cnt, i_memb, N1);
  k_xpool_pull<<<cdiv(NSUP, 8), 256, 0, stream>>>((const float4*)f_xr, a_out, i_rowptrM,
                                                  i_memb, (float4*)f_xpool, NSUP);

  // --- coarse CSR with cw values; degc=rowsum; normalize in place ---
  hipMemsetAsync(i_cnt, 0, (size_t)(NBINS + 1) * 4, stream);
  k_count_coarse<<<gE, 256, 0, stream>>>(dst1, i_cluster, i_cnt, E1C);
  k_scan<<<1, 1024, 0, stream>>>(i_cnt, i_rowptrC, NSUP);
  hipMemsetAsync(i_cnt, 0, (size_t)(NBINS + 1) * 4, stream);
  k_fill_coarse<<<gE, 256, 0, stream>>>(src1, dst1, i_cluster, w1, a_out, i_rowptrC, i_cnt,
                                        i_csrCc, f_csrCv, E1C);
  k_rowsum<<<cdiv(NSUP, 256), 256, 0, stream>>>(i_rowptrC, f_csrCv, f_degc, NSUP);
  k_csrnorm<<<cdiv(NSUP, 256), 256, 0, stream>>>(i_rowptrC, i_csrCc, f_csrCv, f_degc, NSUP);

  // --- coarse conv + MLP1 ---
  k_mm128<<<cdiv(NSUP, 16), 256, 0, stream>>>(f_xpool, wt_c1, b_c1, f_h2, NSUP, 0);
  k_prop<<<cdiv(NSUP, 8), 256, 0, stream>>>((const float4*)f_h2, (float4*)f_h2p, nullptr,
                                            i_rowptrC, i_csrCc, f_csrCv, NSUP);
  k_addrelu<<<cdiv(NSUP * F, 256), 256, 0, stream>>>(f_h2p, f_h2, sup1, NSUP * F);
  k_mm128<<<cdiv(NSUP, 16), 256, 0, stream>>>(sup1, wt_m1, b_m1, sup2, NSUP, 1);

  // --- graph2: CSR + rowsum-norm + GCN in bf16 (decision-free value path) ---
  hipMemsetAsync(i_cnt, 0, (size_t)(NBINS + 1) * 4, stream);
  k_count<<<gE, 256, 0, stream>>>(dsty, i_cnt, E2C);
  k_scan<<<1, 1024, 0, stream>>>(i_cnt, i_rowptr1, N2);
  hipMemsetAsync(i_cnt, 0, (size_t)(NBINS + 1) * 4, stream);
  k_fill<<<gE, 256, 0, stream>>>(dsty, srcy, wy, i_rowptr1, i_cnt, i_csr1c, f_csr1v, E2C);
  k_rowsum<<<gN, 256, 0, stream>>>(i_rowptr1, f_csr1v, f_deg, N2);
  k_csrnorm<<<gN, 256, 0, stream>>>(i_rowptr1, i_csr1c, f_csr1v, f_deg, N2);
  k_mm128_bf16<<<cdiv(N2, 16), 256, 0, stream>>>(y, wt_gcn, b_gcn, h16a, N2);
  {
    const unsigned short* cur = h16a;
    for (int i = 0; i < KHOPS; ++i) {
      int last = (i == KHOPS - 1);
      unsigned short* dst = (i & 1) ? h16a : h16b;
      k_prop_bf16<<<cdiv(N2, 8), 256, 0, stream>>>(
          (const ushort4*)cur, last ? nullptr : (ushort4*)dst,
          last ? (float4*)out_y : nullptr, i_rowptr1, i_csr1c, f_csr1v, N2);
      cur = dst;
    }
  }

  // --- LastLayer ---
  float* f_t1 = f_h2p;  // reuse
  float* f_t2 = f_xr;   // reuse
  k_mm128<<<cdiv(NSUP, 16), 256, 0, stream>>>(sup2, wt_l1, (const float*)nullptr, f_t1, NSUP, 0);
  k_scatter_q<<<cdiv(AC * F, 256), 256, 0, stream>>>(a1, a2, i_cluster, a_out, f_t1, out_y, AC);
  k_mm128<<<cdiv(N1, 16), 256, 0, stream>>>(out_x, wt_l2, (const float*)nullptr, f_t2, N1, 0);
  k_scatter_t2<<<cdiv(AC * F, 256), 256, 0, stream>>>(a1, a2, f_t2, out_y, AC);

  // --- recon ---
  k_mm128<<<cdiv(N2, 16), 256, 0, stream>>>(out_y, wt_m2, b_m2, recon, N2, 0);
}

// Round 5
// 2411.466 us; speedup vs baseline: 1.1059x; 1.1059x over previous
//
#include <hip/hip_runtime.h>
#include <hip/hip_bf16.h>
#include <math.h>

#define N1 50000
#define N2 50000
#define E1C 800000
#define E2C 800000
#define AC 10000
#define F 128
#define NSUP 25000
#define KHOPS 10
#define NEGINF -1e30f
#define NBINS 65536
#define NBINS22 (1 << 22)

static inline int cdiv(int a, int b) { return (a + b - 1) / b; }

// ---------------- bf16 helpers ----------------
__device__ __forceinline__ float bf2f(unsigned short u) {
  return __uint_as_float(((unsigned)u) << 16);
}
__device__ __forceinline__ unsigned short f2bf(float f) {
  unsigned x = __float_as_uint(f);
  return (unsigned short)((x + 0x7FFFu + ((x >> 16) & 1u)) >> 16);
}

// ---------------- CSR build ----------------
__global__ void k_count(const int* __restrict__ key, int* __restrict__ cnt, int n) {
  int e = blockIdx.x * blockDim.x + threadIdx.x;
  if (e < n) atomicAdd(&cnt[key[e]], 1);
}

// single-block scan: thread-sequential partials + shuffle scan
__global__ void k_scan(const int* __restrict__ cnt, int* __restrict__ rowptr, int n) {
  const int T = 1024;
  int t = threadIdx.x;
  int vpt = (n + T - 1) / T;
  int lo = t * vpt, hi = lo + vpt;
  if (hi > n) hi = n;
  int sum = 0;
  for (int i = lo; i < hi; ++i) sum += cnt[i];
  int lane = t & 63, wid = t >> 6;
  int v = sum;
#pragma unroll
  for (int o = 1; o < 64; o <<= 1) {
    int u = __shfl_up(v, o, 64);
    if (lane >= o) v += u;
  }
  __shared__ int wsum[16];
  if (lane == 63) wsum[wid] = v;
  __syncthreads();
  if (t < 16) {
    int w = wsum[t];
#pragma unroll
    for (int o = 1; o < 16; o <<= 1) {
      int u = __shfl_up(w, o, 64);
      if (t >= o) w += u;
    }
    wsum[t] = w;
  }
  __syncthreads();
  int base = (wid ? wsum[wid - 1] : 0) + (v - sum);
  if (t == 0) rowptr[0] = 0;
  int run = base;
  for (int i = lo; i < hi; ++i) { run += cnt[i]; rowptr[i + 1] = run; }
}

__global__ void k_fill(const int* __restrict__ key, const int* __restrict__ payload,
                       const float* __restrict__ val, const int* __restrict__ rowptr,
                       int* __restrict__ cnt, int* __restrict__ col, float* __restrict__ v,
                       int n) {
  int e = blockIdx.x * blockDim.x + threadIdx.x;
  if (e < n) {
    int k = key[e];
    int p = atomicAdd(&cnt[k], 1);
    int s = rowptr[k] + p;
    col[s] = payload[e];
    if (val) v[s] = val[e];
  }
}

// fill storing the element index itself (for cluster->member lists)
__global__ void k_fill_iota(const int* __restrict__ key, const int* __restrict__ rowptr,
                            int* __restrict__ cnt, int* __restrict__ col, int n) {
  int e = blockIdx.x * blockDim.x + threadIdx.x;
  if (e < n) {
    int k = key[e];
    int p = atomicAdd(&cnt[k], 1);
    col[rowptr[k] + p] = e;
  }
}

__global__ void k_count_coarse(const int* __restrict__ dst, const int* __restrict__ cluster,
                               int* __restrict__ cnt, int n) {
  int e = blockIdx.x * blockDim.x + threadIdx.x;
  if (e < n) atomicAdd(&cnt[cluster[dst[e]]], 1);
}

// coarse fill computing cw = w * a[src] * a[dst] inline
__global__ void k_fill_coarse(const int* __restrict__ src, const int* __restrict__ dst,
                              const int* __restrict__ cluster, const float* __restrict__ w,
                              const float* __restrict__ a, const int* __restrict__ rowptr,
                              int* __restrict__ cnt, int* __restrict__ col,
                              float* __restrict__ v, int n) {
  int e = blockIdx.x * blockDim.x + threadIdx.x;
  if (e < n) {
    int sd = dst[e];
    int k = cluster[sd];
    int p = atomicAdd(&cnt[k], 1);
    int s = rowptr[k] + p;
    int ss = src[e];
    col[s] = cluster[ss];
    v[s] = w[e] * a[ss] * a[sd];
  }
}

// ---------------- degree via CSR rowsum (32-lane slice per row) ----------------
__global__ void k_rowsum(const int* __restrict__ rowptr, const float* __restrict__ v,
                         float* __restrict__ deg, int n) {
  int row = blockIdx.x * 8 + (threadIdx.x >> 5);
  if (row >= n) return;
  int q = threadIdx.x & 31;
  int s0 = rowptr[row], s1 = rowptr[row + 1];
  float s = 0.f;
  for (int k = s0 + q; k < s1; k += 32) s += v[k];
#pragma unroll
  for (int o = 16; o; o >>= 1) s += __shfl_xor(s, o, 64);  // stays within aligned 32-group
  if (q == 0) deg[row] = s;
}

// in-place symmetric normalization of CSR values (32-lane slice per row)
__global__ void k_csrnorm(const int* __restrict__ rowptr, const int* __restrict__ col,
                          float* __restrict__ v, const float* __restrict__ deg, int n) {
  int row = blockIdx.x * 8 + (threadIdx.x >> 5);
  if (row >= n) return;
  int q = threadIdx.x & 31;
  int s0 = rowptr[row], s1 = rowptr[row + 1];
  float di = deg[row] + 1.f;
  for (int s = s0 + q; s < s1; s += 32) {
    float dc = deg[col[s]] + 1.f;
    v[s] = v[s] / sqrtf(dc * di);
  }
}

// ---------------- propagation fp32 (pull, 32 threads/node, 8-edge groups) -------------
__global__ void k_prop(const float4* __restrict__ hin, float4* __restrict__ hout,
                       float4* __restrict__ relu_out, const int* __restrict__ rowptr,
                       const int* __restrict__ col, const float* __restrict__ val, int n) {
  int node = blockIdx.x * 8 + (threadIdx.x >> 5);
  if (node >= n) return;
  int q = threadIdx.x & 31;
  int s0 = rowptr[node], s1 = rowptr[node + 1];
  float4 acc = make_float4(0.f, 0.f, 0.f, 0.f);
  for (int s = s0; s < s1; s += 8) {
    int c[8]; float v[8];
#pragma unroll
    for (int j = 0; j < 8; ++j) {
      int ss = s + j;
      int sc = (ss < s1) ? ss : (s1 - 1);
      c[j] = col[sc];
      v[j] = (ss < s1) ? val[sc] : 0.f;
    }
    float4 h[8];
#pragma unroll
    for (int j = 0; j < 8; ++j) h[j] = hin[(size_t)c[j] * 32 + q];
#pragma unroll
    for (int j = 0; j < 8; ++j) {
      acc.x = fmaf(v[j], h[j].x, acc.x);
      acc.y = fmaf(v[j], h[j].y, acc.y);
      acc.z = fmaf(v[j], h[j].z, acc.z);
      acc.w = fmaf(v[j], h[j].w, acc.w);
    }
  }
  hout[(size_t)node * 32 + q] = acc;
  if (relu_out) {
    float4 r;
    r.x = fmaxf(acc.x, 0.f); r.y = fmaxf(acc.y, 0.f);
    r.z = fmaxf(acc.z, 0.f); r.w = fmaxf(acc.w, 0.f);
    relu_out[(size_t)node * 32 + q] = r;
  }
}

// ---------------- propagation bf16 (graph-2, decision-free path) ----------------
__global__ void k_prop_bf16(const ushort4* __restrict__ hin, ushort4* __restrict__ hout,
                            float4* __restrict__ fout, const int* __restrict__ rowptr,
                            const int* __restrict__ col, const float* __restrict__ val, int n) {
  int node = blockIdx.x * 8 + (threadIdx.x >> 5);
  if (node >= n) return;
  int q = threadIdx.x & 31;
  int s0 = rowptr[node], s1 = rowptr[node + 1];
  float4 acc = make_float4(0.f, 0.f, 0.f, 0.f);
  for (int s = s0; s < s1; s += 8) {
    int c[8]; float v[8];
#pragma unroll
    for (int j = 0; j < 8; ++j) {
      int ss = s + j;
      int sc = (ss < s1) ? ss : (s1 - 1);
      c[j] = col[sc];
      v[j] = (ss < s1) ? val[sc] : 0.f;
    }
    ushort4 h[8];
#pragma unroll
    for (int j = 0; j < 8; ++j) h[j] = hin[(size_t)c[j] * 32 + q];
#pragma unroll
    for (int j = 0; j < 8; ++j) {
      acc.x = fmaf(v[j], bf2f(h[j].x), acc.x);
      acc.y = fmaf(v[j], bf2f(h[j].y), acc.y);
      acc.z = fmaf(v[j], bf2f(h[j].z), acc.z);
      acc.w = fmaf(v[j], bf2f(h[j].w), acc.w);
    }
  }
  if (fout) {
    fout[(size_t)node * 32 + q] = acc;
  } else {
    ushort4 o;
    o.x = f2bf(acc.x); o.y = f2bf(acc.y); o.z = f2bf(acc.z); o.w = f2bf(acc.w);
    hout[(size_t)node * 32 + q] = o;
  }
}

// ---------------- dense matmul out = relu?(X @ W + b), W given transposed ----------------
__global__ void k_transpose(const float* __restrict__ W, float* __restrict__ WT) {
  int i = blockIdx.x * blockDim.x + threadIdx.x;
  if (i < F * F) { int k = i >> 7, c = i & 127; WT[c * F + k] = W[i]; }
}

__global__ void k_mm128(const float* __restrict__ X, const float* __restrict__ WT,
                        const float* __restrict__ bias, float* __restrict__ out,
                        int M, int relu) {
  __shared__ float4 xs[16][32];
  int tid = threadIdx.x;
  int c = tid & 127;
  int half = tid >> 7;
  int row0 = blockIdx.x * 16;
  for (int t = tid; t < 512; t += 256) {
    int r = t >> 5, k4 = t & 31;
    int gr = row0 + r;
    float4 v = make_float4(0.f, 0.f, 0.f, 0.f);
    if (gr < M) v = ((const float4*)X)[(size_t)gr * 32 + k4];
    xs[r][k4] = v;
  }
  __syncthreads();
  float acc[8];
#pragma unroll
  for (int r = 0; r < 8; ++r) acc[r] = 0.f;
  const float4* wrow = (const float4*)WT + (size_t)c * 32;
  for (int k4 = 0; k4 < 32; ++k4) {
    float4 w = wrow[k4];
#pragma unroll
    for (int r = 0; r < 8; ++r) {
      float4 xv = xs[half * 8 + r][k4];
      acc[r] = fmaf(xv.x, w.x, acc[r]);
      acc[r] = fmaf(xv.y, w.y, acc[r]);
      acc[r] = fmaf(xv.z, w.z, acc[r]);
      acc[r] = fmaf(xv.w, w.w, acc[r]);
    }
  }
  float bb = bias ? bias[c] : 0.f;
#pragma unroll
  for (int r = 0; r < 8; ++r) {
    int gr = row0 + half * 8 + r;
    if (gr < M) {
      float v = acc[r] + bb;
      if (relu) v = fmaxf(v, 0.f);
      out[(size_t)gr * F + c] = v;
    }
  }
}

// same as k_mm128 but bf16 output
__global__ void k_mm128_bf16(const float* __restrict__ X, const float* __restrict__ WT,
                             const float* __restrict__ bias, unsigned short* __restrict__ out,
                             int M) {
  __shared__ float4 xs[16][32];
  int tid = threadIdx.x;
  int c = tid & 127;
  int half = tid >> 7;
  int row0 = blockIdx.x * 16;
  for (int t = tid; t < 512; t += 256) {
    int r = t >> 5, k4 = t & 31;
    int gr = row0 + r;
    float4 v = make_float4(0.f, 0.f, 0.f, 0.f);
    if (gr < M) v = ((const float4*)X)[(size_t)gr * 32 + k4];
    xs[r][k4] = v;
  }
  __syncthreads();
  float acc[8];
#pragma unroll
  for (int r = 0; r < 8; ++r) acc[r] = 0.f;
  const float4* wrow = (const float4*)WT + (size_t)c * 32;
  for (int k4 = 0; k4 < 32; ++k4) {
    float4 w = wrow[k4];
#pragma unroll
    for (int r = 0; r < 8; ++r) {
      float4 xv = xs[half * 8 + r][k4];
      acc[r] = fmaf(xv.x, w.x, acc[r]);
      acc[r] = fmaf(xv.y, w.y, acc[r]);
      acc[r] = fmaf(xv.z, w.z, acc[r]);
      acc[r] = fmaf(xv.w, w.w, acc[r]);
    }
  }
  float bb = bias ? bias[c] : 0.f;
#pragma unroll
  for (int r = 0; r < 8; ++r) {
    int gr = row0 + half * 8 + r;
    if (gr < M) out[(size_t)gr * F + c] = f2bf(acc[r] + bb);
  }
}

// ---------------- elementwise ----------------
__global__ void k_addrelu(const float* __restrict__ a, const float* __restrict__ b,
                          float* __restrict__ out, int n) {
  int i = blockIdx.x * blockDim.x + threadIdx.x;
  if (i < n) out[i] = fmaxf(a[i] + b[i], 0.f);
}

// ---------------- scores + ranking (top-k via 22-bit bin bucketing) ----------------
__global__ void k_score(const float* __restrict__ xr, const float* __restrict__ p,
                        float* __restrict__ s, int n) {
  int wid = (blockIdx.x * blockDim.x + threadIdx.x) >> 6;
  int lane = threadIdx.x & 63;
  if (wid >= n) return;
  const float* row = xr + (size_t)wid * F;
  float d = row[lane] * p[lane] + row[lane + 64] * p[lane + 64];
#pragma unroll
  for (int o = 32; o; o >>= 1) d += __shfl_xor(d, o, 64);
  if (lane == 0) s[wid] = d;
}

__device__ __forceinline__ unsigned sortkey(float f) {
  if (f == 0.f) f = 0.f;  // canonicalize -0 -> +0
  unsigned u = __float_as_uint(f);
  return (u & 0x80000000u) ? ~u : (u | 0x80000000u);
}

__global__ void k_key(const float* __restrict__ s, unsigned* __restrict__ key, int n) {
  int i = blockIdx.x * blockDim.x + threadIdx.x;
  if (i < n) key[i] = sortkey(s[i]);
}

__global__ void k_count_bins22(const unsigned* __restrict__ key, int* __restrict__ cnt, int n) {
  int i = blockIdx.x * blockDim.x + threadIdx.x;
  if (i < n) atomicAdd(&cnt[key[i] >> 10], 1);
}

// block sums over 1024-bin chunks (grid = NBINS22/1024 = 4096 blocks, 256 thr)
__global__ void k_hist_blocksum(const int* __restrict__ cnt, int* __restrict__ partial) {
  int t = threadIdx.x;
  int base = blockIdx.x * 1024 + t * 4;
  int s = cnt[base] + cnt[base + 1] + cnt[base + 2] + cnt[base + 3];
#pragma unroll
  for (int o = 32; o; o >>= 1) s += __shfl_down(s, o, 64);
  __shared__ int ws[4];
  int lane = t & 63, w = t >> 6;
  if (lane == 0) ws[w] = s;
  __syncthreads();
  if (t == 0) partial[blockIdx.x] = ws[0] + ws[1] + ws[2] + ws[3];
}

// apply scanned partials: binptr[b+1] = global inclusive prefix
__global__ void k_hist_apply(const int* __restrict__ cnt, const int* __restrict__ partialptr,
                             int* __restrict__ binptr) {
  int t = threadIdx.x;
  int base = blockIdx.x * 1024 + t * 4;
  int c0 = cnt[base], c1 = cnt[base + 1], c2 = cnt[base + 2], c3 = cnt[base + 3];
  int s = c0 + c1 + c2 + c3;
  int lane = t & 63, w = t >> 6;
  int v = s;
#pragma unroll
  for (int o = 1; o < 64; o <<= 1) {
    int u = __shfl_up(v, o, 64);
    if (lane >= o) v += u;
  }
  __shared__ int ws[4];
  if (lane == 63) ws[w] = v;
  __syncthreads();
  int wb = 0;
  for (int i = 0; i < w; ++i) wb += ws[i];
  int run = partialptr[blockIdx.x] + wb + (v - s);
  binptr[base + 1] = run + c0;
  binptr[base + 2] = run + c0 + c1;
  binptr[base + 3] = run + c0 + c1 + c2;
  binptr[base + 4] = run + s;
  if (blockIdx.x == 0 && t == 0) binptr[0] = 0;
}

__global__ void k_fill_bins22(const unsigned* __restrict__ key, const int* __restrict__ binptr,
                              int* __restrict__ cnt, int* __restrict__ bidx,
                              unsigned* __restrict__ bkey, int n) {
  int i = blockIdx.x * blockDim.x + threadIdx.x;
  if (i < n) {
    unsigned k = key[i];
    int b = k >> 10;
    int p = atomicAdd(&cnt[b], 1);
    int s = binptr[b] + p;
    bidx[s] = i;
    bkey[s] = k;
  }
}

// rank_i = #{j: s_j > s_i} + #{j: s_j == s_i && j < i}; supid = rank < NSUP ? rank : -1
__global__ void k_rank22(const unsigned* __restrict__ key, const int* __restrict__ binptr,
                         const int* __restrict__ bidx, const unsigned* __restrict__ bkey,
                         int* __restrict__ supid, int n) {
  int i = blockIdx.x * blockDim.x + threadIdx.x;
  if (i >= n) return;
  unsigned ki = key[i];
  int b = ki >> 10;
  int cnt = n - binptr[b + 1];  // all keys in strictly-higher bins
  int s1 = binptr[b + 1];
  for (int s = binptr[b]; s < s1; ++s) {
    unsigned kj = bkey[s];
    cnt += (kj > ki) || (kj == ki && bidx[s] < i);
  }
  supid[i] = (cnt < NSUP) ? cnt : -1;
}

// ---------------- attention / assignment ----------------
__device__ __forceinline__ float read_T(const void* p) {
  int ib = *(const int*)p;
  float fb = __int_as_float(ib);
  if (ib >= 1 && ib < (1 << 20)) return (float)ib;   // int-encoded scalar
  if (fb > 1e-6f && fb < 1e6f) return fb;            // float-encoded scalar
  return 1.0f;
}

// wave per node; 4-edge groups for gather MLP
__global__ void k_att_a(const float* __restrict__ xr, const int* __restrict__ rowptr,
                        const int* __restrict__ col, const int* __restrict__ supid,
                        const void* __restrict__ tptr, float* __restrict__ att,
                        float* __restrict__ attself, float* __restrict__ mout, int n) {
  int wid = (blockIdx.x * blockDim.x + threadIdx.x) >> 6;
  int lane = threadIdx.x & 63;
  if (wid >= n) return;
  float inv = 1.0f / (sqrtf(128.0f) * read_T(tptr));
  const float* xn = xr + (size_t)wid * F;
  float x0 = xn[lane], x1 = xn[lane + 64];
  // self candidate
  float d = x0 * x0 + x1 * x1;
#pragma unroll
  for (int o = 32; o; o >>= 1) d += __shfl_xor(d, o, 64);
  float av = (supid[wid] >= 0) ? d * inv : NEGINF;
  float m = av;
  if (lane == 0) attself[wid] = av;
  int s0 = rowptr[wid], s1 = rowptr[wid + 1];
  for (int s = s0; s < s1; s += 4) {
    int c[4]; bool ok[4];
#pragma unroll
    for (int j = 0; j < 4; ++j) {
      int ss = s + j;
      ok[j] = ss < s1;
      c[j] = col[ok[j] ? ss : (s1 - 1)];
    }
    float dd[4];
#pragma unroll
    for (int j = 0; j < 4; ++j) {
      const float* xc = xr + (size_t)c[j] * F;
      dd[j] = x0 * xc[lane] + x1 * xc[lane + 64];
    }
#pragma unroll
    for (int j = 0; j < 4; ++j) {
#pragma unroll
      for (int o = 32; o; o >>= 1) dd[j] += __shfl_xor(dd[j], o, 64);
    }
#pragma unroll
    for (int j = 0; j < 4; ++j) {
      if (ok[j]) {
        float a2 = (supid[c[j]] >= 0) ? dd[j] * inv : NEGINF;
        if (lane == 0) att[s + j] = a2;
        m = fmaxf(m, a2);
      }
    }
  }
  if (lane == 0) mout[wid] = m;
}

// 32-lane slice per node: esum = sum exp(att-m), best = max supid among argmax cands
__global__ void k_att_b(const int* __restrict__ rowptr, const int* __restrict__ col,
                        const int* __restrict__ supid, const float* __restrict__ att,
                        const float* __restrict__ attself, const float* __restrict__ mv,
                        int* __restrict__ cluster, float* __restrict__ aout, int n) {
  int i = blockIdx.x * 8 + (threadIdx.x >> 5);
  if (i >= n) return;
  int q = threadIdx.x & 31;
  float m = mv[i];
  float as = attself[i];
  float esum = 0.f;
  int best = -1;
  if (q == 0) {
    esum = expf(as - m);
    if (as >= m) best = supid[i];
  }
  int s0 = rowptr[i], s1 = rowptr[i + 1];
  for (int s = s0 + q; s < s1; s += 32) {
    float av = att[s];
    esum += expf(av - m);
    if (av >= m) {
      int sid = supid[col[s]];
      if (sid > best) best = sid;
    }
  }
#pragma unroll
  for (int o = 16; o; o >>= 1) {
    esum += __shfl_xor(esum, o, 64);
    int ob = __shfl_xor(best, o, 64);
    if (ob > best) best = ob;
  }
  if (q == 0) {
    int has = best >= 0;
    cluster[i] = has ? best : 0;
    aout[i] = has ? 1.0f / esum : 0.0f;
  }
}

// ---------------- pooling (pull over cluster->member CSR) ----------------
__global__ void k_xpool_pull(const float4* __restrict__ xr, const float* __restrict__ a,
                             const int* __restrict__ rowptrM, const int* __restrict__ memb,
                             float4* __restrict__ xpool, int n) {
  int c = blockIdx.x * 8 + (threadIdx.x >> 5);
  if (c >= n) return;
  int q = threadIdx.x & 31;
  int s0 = rowptrM[c], s1 = rowptrM[c + 1];
  float4 acc = make_float4(0.f, 0.f, 0.f, 0.f);
  for (int s = s0; s < s1; ++s) {
    int m = memb[s];
    float av = a[m];
    float4 h = xr[(size_t)m * 32 + q];
    acc.x = fmaf(av, h.x, acc.x);
    acc.y = fmaf(av, h.y, acc.y);
    acc.z = fmaf(av, h.z, acc.z);
    acc.w = fmaf(av, h.w, acc.w);
  }
  xpool[(size_t)c * 32 + q] = acc;
}

// ---------------- anchor scatters ----------------
__global__ void k_scatter_q(const int* __restrict__ a1, const int* __restrict__ a2,
                            const int* __restrict__ cluster, const float* __restrict__ aarr,
                            const float* __restrict__ t1, float* __restrict__ outy, int nA) {
  int idx = blockIdx.x * blockDim.x + threadIdx.x;
  if (idx >= nA * F) return;
  int k = idx >> 7, f = idx & 127;
  int n1 = a1[k];
  float qw = aarr[n1];
  if (qw != 0.f)
    atomicAdd(&outy[(size_t)a2[k] * F + f], qw * t1[(size_t)cluster[n1] * F + f]);
}

__global__ void k_scatter_t2(const int* __restrict__ a1, const int* __restrict__ a2,
                             const float* __restrict__ t2, float* __restrict__ outy, int nA) {
  int idx = blockIdx.x * blockDim.x + threadIdx.x;
  if (idx >= nA * F) return;
  int k = idx >> 7, f = idx & 127;
  atomicAdd(&outy[(size_t)a2[k] * F + f], t2[(size_t)a1[k] * F + f]);
}

// ================= host =================
extern "C" void kernel_launch(void* const* d_in, const int* in_sizes, int n_in,
                              void* d_out, int out_size, void* d_ws, size_t ws_size,
                              hipStream_t stream) {
  (void)in_sizes; (void)n_in; (void)out_size; (void)ws_size;
  const float* x   = (const float*)d_in[0];
  const int*   ei  = (const int*)d_in[1];     // src = ei, dst = ei+E1C
  const float* w1  = (const float*)d_in[2];
  const float* y   = (const float*)d_in[3];
  const int*   eiy = (const int*)d_in[4];
  const float* wy  = (const float*)d_in[5];
  const int*   anc = (const int*)d_in[6];     // a1 = anc, a2 = anc+AC
  const void*  tmp = d_in[7];
  const float* W_gcn = (const float*)d_in[8];
  const float* b_gcn = (const float*)d_in[9];
  const float* p_sc  = (const float*)d_in[10];
  const float* W_c1  = (const float*)d_in[11];
  const float* b_c1  = (const float*)d_in[12];
  const float* W_m1  = (const float*)d_in[13];
  const float* b_m1  = (const float*)d_in[14];
  const float* W_l1  = (const float*)d_in[15];
  const float* W_l2  = (const float*)d_in[16];
  const float* W_m2  = (const float*)d_in[17];
  const float* b_m2  = (const float*)d_in[18];

  float* out   = (float*)d_out;
  float* out_x = out;
  float* sup1  = out_x + (size_t)N1 * F;
  float* out_y = sup1 + (size_t)NSUP * F;
  float* sup2  = out_y + (size_t)N2 * F;
  float* a_out = sup2 + (size_t)NSUP * F;
  float* recon = a_out + N1;

  char* wsb = (char*)d_ws;
  size_t off = 0;
  auto alloc = [&](size_t bytes) -> void* {
    void* p = wsb + off;
    off = (off + bytes + 255) & ~(size_t)255;
    return p;
  };
  float*    f_csr1v   = (float*)alloc((size_t)E1C * 4);          // reused for graph2 CSR val
  int*      i_csr1c   = (int*)alloc((size_t)E1C * 4);            // reused for graph2 CSR col
  int*      i_rowptr1 = (int*)alloc((size_t)(N1 + 1) * 4);       // reused for graph2
  float*    f_deg     = (float*)alloc((size_t)N1 * 4);           // reused for graph2
  int*      i_cnt     = (int*)alloc((size_t)(NBINS + 1) * 4);
  float*    f_ha      = (float*)alloc((size_t)N1 * F * 4);       // g1 h / cnt22 / g2 bf16 h_a
  float*    f_hb      = (float*)alloc((size_t)N1 * F * 4);       // g1 h / binptr22 / g2 bf16 h_b
  float*    f_xr      = (float*)alloc((size_t)N1 * F * 4);       // reused for t2
  float*    f_s       = (float*)alloc((size_t)N1 * 4);
  unsigned* u_key     = (unsigned*)alloc((size_t)N1 * 4);
  int*      i_partial = (int*)alloc((size_t)4096 * 4);
  int*      i_partptr = (int*)alloc((size_t)4097 * 4);
  int*      i_bidx    = (int*)alloc((size_t)N1 * 4);
  unsigned* u_bkey    = (unsigned*)alloc((size_t)N1 * 4);
  int*      i_supid   = (int*)alloc((size_t)N1 * 4);
  int*      i_rowptrS = (int*)alloc((size_t)(N1 + 1) * 4);
  int*      i_csrSc   = (int*)alloc((size_t)E1C * 4);
  float*    f_att     = (float*)alloc((size_t)E1C * 4);
  float*    f_attself = (float*)alloc((size_t)N1 * 4);
  float*    f_m       = (float*)alloc((size_t)N1 * 4);
  int*      i_cluster = (int*)alloc((size_t)N1 * 4);
  float*    f_xpool   = (float*)alloc((size_t)NSUP * F * 4);
  float*    f_degc    = (float*)alloc((size_t)NSUP * 4);
  int*      i_rowptrC = (int*)alloc((size_t)(NSUP + 1) * 4);
  int*      i_csrCc   = (int*)alloc((size_t)E1C * 4);
  float*    f_csrCv   = (float*)alloc((size_t)E1C * 4);
  int*      i_rowptrM = (int*)alloc((size_t)(NSUP + 1) * 4);
  int*      i_memb    = (int*)alloc((size_t)N1 * 4);
  float*    f_h2      = (float*)alloc((size_t)NSUP * F * 4);
  float*    f_h2p     = (float*)alloc((size_t)NSUP * F * 4);     // reused for t1
  float*    f_wt      = (float*)alloc((size_t)6 * F * F * 4);

  // overlays: rank bins live between graph-1 and graph-2; bf16 h lives in graph-2 only
  int* i_cnt22    = (int*)f_ha;       // 16 MB <= 25.6 MB
  int* i_binptr22 = (int*)f_hb;       // 16 MB + 4 <= 25.6 MB
  unsigned short* h16a = (unsigned short*)f_ha;   // 12.8 MB
  unsigned short* h16b = (unsigned short*)f_hb;   // 12.8 MB

  const int* src1 = ei,  * dst1 = ei + E1C;
  const int* srcy = eiy, * dsty = eiy + E2C;
  const int* a1 = anc, * a2 = anc + AC;

  // --- transpose all weights ---
  const float* Ws[6] = { W_gcn, W_c1, W_m1, W_l1, W_l2, W_m2 };
  for (int i = 0; i < 6; ++i)
    k_transpose<<<cdiv(F * F, 256), 256, 0, stream>>>(Ws[i], f_wt + (size_t)i * F * F);
  float* wt_gcn = f_wt, *wt_c1 = f_wt + 16384, *wt_m1 = f_wt + 2 * 16384,
       * wt_l1 = f_wt + 3 * 16384, *wt_l2 = f_wt + 4 * 16384, *wt_m2 = f_wt + 5 * 16384;

  int gE = cdiv(E1C, 256);
  int gN = cdiv(N1, 256);
  int gN8 = cdiv(N1, 8);      // 32-lane-slice-per-row launches
  int gC8 = cdiv(NSUP, 8);

  // --- CSR graph1 by dst, with raw w; then deg=rowsum, normalize in place ---
  hipMemsetAsync(i_cnt, 0, (size_t)(NBINS + 1) * 4, stream);
  k_count<<<gE, 256, 0, stream>>>(dst1, i_cnt, E1C);
  k_scan<<<1, 1024, 0, stream>>>(i_cnt, i_rowptr1, N1);
  hipMemsetAsync(i_cnt, 0, (size_t)(NBINS + 1) * 4, stream);
  k_fill<<<gE, 256, 0, stream>>>(dst1, src1, w1, i_rowptr1, i_cnt, i_csr1c, f_csr1v, E1C);
  k_rowsum<<<gN8, 256, 0, stream>>>(i_rowptr1, f_csr1v, f_deg, N1);
  k_csrnorm<<<gN8, 256, 0, stream>>>(i_rowptr1, i_csr1c, f_csr1v, f_deg, N1);

  // --- GCN graph1: h0 = x@W + b; 10 hops (fp32 — feeds top-k/argmax decisions) ---
  k_mm128<<<cdiv(N1, 16), 256, 0, stream>>>(x, wt_gcn, b_gcn, f_ha, N1, 0);
  {
    const float* cur = f_ha;
    for (int i = 0; i < KHOPS; ++i) {
      int last = (i == KHOPS - 1);
      float* dst = last ? out_x : ((i & 1) ? f_ha : f_hb);
      k_prop<<<gN8, 256, 0, stream>>>((const float4*)cur, (float4*)dst,
                                      last ? (float4*)f_xr : nullptr,
                                      i_rowptr1, i_csr1c, f_csr1v, N1);
      cur = dst;
    }
  }

  // --- scores + top-k ranks (22-bit bins) ---
  k_score<<<cdiv(N1, 4), 256, 0, stream>>>(f_xr, p_sc, f_s, N1);
  k_key<<<gN, 256, 0, stream>>>(f_s, u_key, N1);
  hipMemsetAsync(i_cnt22, 0, (size_t)NBINS22 * 4, stream);
  k_count_bins22<<<gN, 256, 0, stream>>>(u_key, i_cnt22, N1);
  k_hist_blocksum<<<NBINS22 / 1024, 256, 0, stream>>>(i_cnt22, i_partial);
  k_scan<<<1, 1024, 0, stream>>>(i_partial, i_partptr, 4096);
  k_hist_apply<<<NBINS22 / 1024, 256, 0, stream>>>(i_cnt22, i_partptr, i_binptr22);
  hipMemsetAsync(i_cnt22, 0, (size_t)NBINS22 * 4, stream);
  k_fill_bins22<<<gN, 256, 0, stream>>>(u_key, i_binptr22, i_cnt22, i_bidx, u_bkey, N1);
  k_rank22<<<gN, 256, 0, stream>>>(u_key, i_binptr22, i_bidx, u_bkey, i_supid, N1);

  // --- CSR graph1 by src (attention candidates) ---
  hipMemsetAsync(i_cnt, 0, (size_t)(NBINS + 1) * 4, stream);
  k_count<<<gE, 256, 0, stream>>>(src1, i_cnt, E1C);
  k_scan<<<1, 1024, 0, stream>>>(i_cnt, i_rowptrS, N1);
  hipMemsetAsync(i_cnt, 0, (size_t)(NBINS + 1) * 4, stream);
  k_fill<<<gE, 256, 0, stream>>>(src1, dst1, (const float*)nullptr, i_rowptrS, i_cnt, i_csrSc,
                                 (float*)nullptr, E1C);

  // --- attention passes ---
  k_att_a<<<cdiv(N1, 4), 256, 0, stream>>>(f_xr, i_rowptrS, i_csrSc, i_supid, tmp,
                                           f_att, f_attself, f_m, N1);
  k_att_b<<<gN8, 256, 0, stream>>>(i_rowptrS, i_csrSc, i_supid, f_att, f_attself,
                                   f_m, i_cluster, a_out, N1);

  // --- coarsen: cluster->member CSR + pull pooling (no fp32 atomics) ---
  hipMemsetAsync(i_cnt, 0, (size_t)(NBINS + 1) * 4, stream);
  k_count<<<gN, 256, 0, stream>>>(i_cluster, i_cnt, N1);
  k_scan<<<1, 1024, 0, stream>>>(i_cnt, i_rowptrM, NSUP);
  hipMemsetAsync(i_cnt, 0, (size_t)(NBINS + 1) * 4, stream);
  k_fill_iota<<<gN, 256, 0, stream>>>(i_cluster, i_rowptrM, i_cnt, i_memb, N1);
  k_xpool_pull<<<gC8, 256, 0, stream>>>((const float4*)f_xr, a_out, i_rowptrM,
                                        i_memb, (float4*)f_xpool, NSUP);

  // --- coarse CSR with cw values; degc=rowsum; normalize in place ---
  hipMemsetAsync(i_cnt, 0, (size_t)(NBINS + 1) * 4, stream);
  k_count_coarse<<<gE, 256, 0, stream>>>(dst1, i_cluster, i_cnt, E1C);
  k_scan<<<1, 1024, 0, stream>>>(i_cnt, i_rowptrC, NSUP);
  hipMemsetAsync(i_cnt, 0, (size_t)(NBINS + 1) * 4, stream);
  k_fill_coarse<<<gE, 256, 0, stream>>>(src1, dst1, i_cluster, w1, a_out, i_rowptrC, i_cnt,
                                        i_csrCc, f_csrCv, E1C);
  k_rowsum<<<gC8, 256, 0, stream>>>(i_rowptrC, f_csrCv, f_degc, NSUP);
  k_csrnorm<<<gC8, 256, 0, stream>>>(i_rowptrC, i_csrCc, f_csrCv, f_degc, NSUP);

  // --- coarse conv + MLP1 ---
  k_mm128<<<cdiv(NSUP, 16), 256, 0, stream>>>(f_xpool, wt_c1, b_c1, f_h2, NSUP, 0);
  k_prop<<<gC8, 256, 0, stream>>>((const float4*)f_h2, (float4*)f_h2p, nullptr,
                                  i_rowptrC, i_csrCc, f_csrCv, NSUP);
  k_addrelu<<<cdiv(NSUP * F, 256), 256, 0, stream>>>(f_h2p, f_h2, sup1, NSUP * F);
  k_mm128<<<cdiv(NSUP, 16), 256, 0, stream>>>(sup1, wt_m1, b_m1, sup2, NSUP, 1);

  // --- graph2: CSR + rowsum-norm + GCN in bf16 (decision-free value path) ---
  hipMemsetAsync(i_cnt, 0, (size_t)(NBINS + 1) * 4, stream);
  k_count<<<gE, 256, 0, stream>>>(dsty, i_cnt, E2C);
  k_scan<<<1, 1024, 0, stream>>>(i_cnt, i_rowptr1, N2);
  hipMemsetAsync(i_cnt, 0, (size_t)(NBINS + 1) * 4, stream);
  k_fill<<<gE, 256, 0, stream>>>(dsty, srcy, wy, i_rowptr1, i_cnt, i_csr1c, f_csr1v, E2C);
  k_rowsum<<<gN8, 256, 0, stream>>>(i_rowptr1, f_csr1v, f_deg, N2);
  k_csrnorm<<<gN8, 256, 0, stream>>>(i_rowptr1, i_csr1c, f_csr1v, f_deg, N2);
  k_mm128_bf16<<<cdiv(N2, 16), 256, 0, stream>>>(y, wt_gcn, b_gcn, h16a, N2);
  {
    const unsigned short* cur = h16a;
    for (int i = 0; i < KHOPS; ++i) {
      int last = (i == KHOPS - 1);
      unsigned short* dst = (i & 1) ? h16a : h16b;
      k_prop_bf16<<<gN8, 256, 0, stream>>>(
          (const ushort4*)cur, last ? nullptr : (ushort4*)dst,
          last ? (float4*)out_y : nullptr, i_rowptr1, i_csr1c, f_csr1v, N2);
      cur = dst;
    }
  }

  // --- LastLayer ---
  float* f_t1 = f_h2p;  // reuse
  float* f_t2 = f_xr;   // reuse
  k_mm128<<<cdiv(NSUP, 16), 256, 0, stream>>>(sup2, wt_l1, (const float*)nullptr, f_t1, NSUP, 0);
  k_scatter_q<<<cdiv(AC * F, 256), 256, 0, stream>>>(a1, a2, i_cluster, a_out, f_t1, out_y, AC);
  k_mm128<<<cdiv(N1, 16), 256, 0, stream>>>(out_x, wt_l2, (const float*)nullptr, f_t2, N1, 0);
  k_scatter_t2<<<cdiv(AC * F, 256), 256, 0, stream>>>(a1, a2, f_t2, out_y, AC);

  // --- recon ---
  k_mm128<<<cdiv(N2, 16), 256, 0, stream>>>(out_y, wt_m2, b_m2, recon, N2, 0);
}